// Round 10
// baseline (179.942 us; speedup 1.0000x reference)
//
#include <hip/hip_runtime.h>
#include <math.h>

using u16 = unsigned short;
typedef __attribute__((ext_vector_type(8))) __bf16 bf16x8;
typedef __attribute__((ext_vector_type(4))) float f32x4;
typedef __attribute__((ext_vector_type(4))) float f4v;
typedef __attribute__((ext_vector_type(8))) u16 u16x8;

__device__ __forceinline__ u16 f2bf(float f) {
  unsigned u = __float_as_uint(f);
  u += 0x7fffu + ((u >> 16) & 1u);   // round-to-nearest-even
  return (u16)(u >> 16);
}
__device__ __forceinline__ float bf2f(u16 b) {
  unsigned u = ((unsigned)b) << 16;
  return __uint_as_float(u);
}

__device__ __forceinline__ void gload16(const void* g, void* l) {
  __builtin_amdgcn_global_load_lds(
      (const __attribute__((address_space(1))) unsigned int*)g,
      (__attribute__((address_space(3))) unsigned int*)l, 16, 0, 0);
}

__device__ __forceinline__ f32x4 MF(bf16x8 a, bf16x8 b, f32x4 c) {
  return __builtin_amdgcn_mfma_f32_16x16x32_bf16(a, b, c, 0, 0, 0);
}

// ---------------------------------------------------------------- cast f32->bf16 (3 tensors)
__global__ __launch_bounds__(256) void cast3_f32_bf16(
    const float* __restrict__ p0, const float* __restrict__ p1,
    const float* __restrict__ p2, u16* __restrict__ out, size_t ostride) {
  int z = blockIdx.z;
  const float* in = (z == 0) ? p0 : (z == 1) ? p1 : p2;
  size_t i = ((size_t)blockIdx.x * 256 + threadIdx.x) * 8;
  f4v a = *reinterpret_cast<const f4v*>(in + i);
  f4v b = *reinterpret_cast<const f4v*>(in + i + 4);
  u16x8 r;
  r[0] = f2bf(a[0]); r[1] = f2bf(a[1]); r[2] = f2bf(a[2]); r[3] = f2bf(a[3]);
  r[4] = f2bf(b[0]); r[5] = f2bf(b[1]); r[6] = f2bf(b[2]); r[7] = f2bf(b[3]);
  *reinterpret_cast<u16x8*>(out + z * ostride + i) = r;
}

// ---------------------------------------------------------------- bf16 transpose
// in: [4][2048][1024]  -> out: [4][1024][2048]
__global__ __launch_bounds__(256) void transpose_bf16k(const u16* __restrict__ in,
                                                       u16* __restrict__ out) {
  __shared__ u16 t[64][65];
  int c0 = blockIdx.x * 64, r0 = blockIdx.y * 64;
  size_t zb = (size_t)blockIdx.z * 2048 * 1024;
  const u16* I = in + zb;
  u16* O = out + zb;
  int tx = threadIdx.x & 63, ty = threadIdx.x >> 6;
  #pragma unroll
  for (int i = 0; i < 64; i += 4)
    t[ty + i][tx] = I[(size_t)(r0 + ty + i) * 1024 + c0 + tx];
  __syncthreads();
  #pragma unroll
  for (int i = 0; i < 64; i += 4)
    O[(size_t)(c0 + ty + i) * 2048 + r0 + tx] = t[tx][ty + i];
}

// ================================================================ 8-wave 128x128 GEMM
// 2-phase dbuf, 512 threads = 8 waves (2M x 4N; wave out 64x32, acc[4][2],
// 8 MFMA/iter). Staging: wave w owns A-chunk w + B-chunk w (1KB each).
// MODE 1: causal QK^T, tri-packed, XCD-swizzled, bf16 out (alpha pre-scale).
// MODE 2: causal PV, K clipped to (bm+1)*128, longest-first, f32 out.
// MODE 3: stacked 3-way projection: A rows globally stacked [3*8192][1024];
//         weight slab B + which*sB; output {C, C1, C2}; XCD-chunked grid 1536.
template<typename OutT, int MODE>
__global__ __launch_bounds__(512) void gemm_bt8(
    const u16* __restrict__ A, const u16* __restrict__ B, OutT* __restrict__ C,
    int K, int lda, int ldb, int ldc,
    size_t sA, size_t sB, size_t sC, float alpha,
    OutT* __restrict__ C1, OutT* __restrict__ C2) {
  int bn, bm, bz = 0;
  int kEnd = K;
  const u16 *Ag, *Bg;
  OutT* Cg;
  if (MODE == 1) {                       // grid 544 = 4 * 136 lower-tri tiles
    int h = blockIdx.x;
    int l = (h & 7) * 68 + (h >> 3);
    bz = l / 136;
    int t = l % 136;
    bm = (int)((sqrtf(8.f * (float)t + 1.f) - 1.f) * 0.5f);
    while ((bm + 1) * (bm + 2) / 2 <= t) ++bm;
    while (bm * (bm + 1) / 2 > t) --bm;
    bn = t - bm * (bm + 1) / 2;
    Ag = A + sA * bz + (size_t)bm * 128 * lda;
    Bg = B + sB * bz + (size_t)bn * 128 * ldb;
    Cg = C + sC * bz;
  } else if (MODE == 2) {                // grid 512
    int l = blockIdx.x;
    bm = 15 - (l >> 5);                  // longest kEnd first
    int rest = l & 31;
    bz = rest >> 3;
    bn = rest & 7;
    kEnd = (K < (bm + 1) * 128) ? K : (bm + 1) * 128;
    Ag = A + sA * bz + (size_t)bm * 128 * lda;
    Bg = B + sB * bz + (size_t)bn * 128 * ldb;
    Cg = C + sC * bz;
  } else {                               // MODE 3, grid 1536, XCD-chunked
    int h = blockIdx.x;
    int l = (h & 7) * 192 + (h >> 3);
    bn = l & 7;
    int bm192 = l >> 3;
    int which = bm192 >> 6;
    bm = bm192 & 63;
    Ag = A + (size_t)bm192 * 128 * lda;
    Bg = B + (size_t)which * sB + (size_t)bn * 128 * ldb;
    Cg = (which == 0) ? C : (which == 1) ? C1 : C2;
  }

  __shared__ __align__(16) u16 As[2][128 * 32];
  __shared__ __align__(16) u16 Bs[2][128 * 32];

  const int tid = threadIdx.x;
  const int lane = tid & 63, wv = tid >> 6;   // 8 waves
  const int wr = wv >> 2, wc = wv & 3;        // 2M x 4N
  const int fr = lane & 15, kq = (lane >> 4) * 8;

  // staging: wave wv owns A-chunk wv + B-chunk wv (1KB each)
  const int e0 = wv * 512 + lane * 8;
  const int r0 = e0 >> 5, c0 = e0 & 31;
  const u16* a0 = Ag + (size_t)r0 * lda + c0;
  const u16* b0 = Bg + (size_t)r0 * ldb + c0;

  f32x4 acc[4][2] = {};
  const int nt = kEnd / 32;

  gload16(a0, &As[0][wv * 512]);
  gload16(b0, &Bs[0][wv * 512]);
  __syncthreads();

  for (int t = 0; t < nt; ++t) {
    const int cur = t & 1;
    if (t + 1 < nt) {
      const int k0 = (t + 1) * 32;
      gload16(a0 + k0, &As[cur ^ 1][wv * 512]);
      gload16(b0 + k0, &Bs[cur ^ 1][wv * 512]);
    }
    bf16x8 af[4], bfv[2];
    #pragma unroll
    for (int m = 0; m < 4; ++m)
      af[m] = *reinterpret_cast<const bf16x8*>(&As[cur][(wr * 64 + m * 16 + fr) * 32 + kq]);
    #pragma unroll
    for (int n = 0; n < 2; ++n)
      bfv[n] = *reinterpret_cast<const bf16x8*>(&Bs[cur][(wc * 32 + n * 16 + fr) * 32 + kq]);
    #pragma unroll
    for (int m = 0; m < 4; ++m)
      #pragma unroll
      for (int n = 0; n < 2; ++n)
        acc[m][n] = MF(af[m], bfv[n], acc[m][n]);
    __syncthreads();
  }

  const int row0 = bm * 128 + wr * 64 + (lane >> 4) * 4;
  const int col0 = bn * 128 + wc * 32 + fr;
  #pragma unroll
  for (int m = 0; m < 4; ++m)
    #pragma unroll
    for (int n = 0; n < 2; ++n) {
      #pragma unroll
      for (int j = 0; j < 4; ++j) {
        float val = acc[m][n][j] * alpha;
        size_t idx = (size_t)(row0 + m * 16 + j) * ldc + (col0 + n * 16);
        if constexpr (sizeof(OutT) == 2) Cg[idx] = f2bf(val);
        else Cg[idx] = val;
      }
    }
}

// ---------------------------------------------------------------- causal softmax (bf16 in/out, in-place)
// scores: [4][2048][2048] bf16. Row r: softmax over t<=s, write bf16 P in place.
__global__ __launch_bounds__(256) void softmax_causal(u16* __restrict__ sc) {
  int r = blockIdx.x;          // 0..8191
  int s = r & 2047;
  u16* row = sc + (size_t)r * 2048;
  int tid = threadIdx.x;
  int t0 = tid * 8;
  u16x8 raw = {0, 0, 0, 0, 0, 0, 0, 0};
  if (t0 <= s) raw = *reinterpret_cast<const u16x8*>(row + t0);
  float v[8];
  float mx = -1e30f;
  #pragma unroll
  for (int j = 0; j < 8; ++j) {
    v[j] = ((t0 + j) <= s) ? bf2f(raw[j]) : -1e30f;
    mx = fmaxf(mx, v[j]);
  }
  #pragma unroll
  for (int o = 32; o; o >>= 1) mx = fmaxf(mx, __shfl_xor(mx, o, 64));
  __shared__ float red[8];
  if ((tid & 63) == 0) red[tid >> 6] = mx;
  __syncthreads();
  mx = fmaxf(fmaxf(red[0], red[1]), fmaxf(red[2], red[3]));
  float p[8];
  float sum = 0.f;
  #pragma unroll
  for (int j = 0; j < 8; ++j) {
    p[j] = ((t0 + j) <= s) ? __expf(v[j] - mx) : 0.f;
    sum += p[j];
  }
  #pragma unroll
  for (int o = 32; o; o >>= 1) sum += __shfl_xor(sum, o, 64);
  if ((tid & 63) == 0) red[4 + (tid >> 6)] = sum;
  __syncthreads();
  sum = red[4] + red[5] + red[6] + red[7];
  float inv = 1.0f / sum;
  u16x8 o8;
  #pragma unroll
  for (int j = 0; j < 8; ++j) o8[j] = f2bf(p[j] * inv);
  if (t0 <= (s | 127))   // PV reads cols < (bm+1)*128 only
    *reinterpret_cast<u16x8*>(row + t0) = o8;
}

// ---------------------------------------------------------------- launcher
extern "C" void kernel_launch(void* const* d_in, const int* in_sizes, int n_in,
                              void* d_out, int out_size, void* d_ws, size_t ws_size,
                              hipStream_t stream) {
  const float* q  = (const float*)d_in[0];
  const float* k  = (const float*)d_in[1];
  const float* v  = (const float*)d_in[2];
  // d_in[3] = attn_mask (causal tril) — handled analytically
  const float* Wq = (const float*)d_in[4];
  const float* Wk = (const float*)d_in[5];
  const float* Wv = (const float*)d_in[6];
  float* out = (float*)d_out;
  char* ws = (char*)d_ws;

  const size_t MB = 1024ull * 1024ull;
  // Liveness: qb/wqb dead after proj; Vp dead after transpose; sc (32MB bf16
  // scores) overlays them, written at QK.
  u16* sc   = (u16*)ws;               // 0..32MB  bf16 scores [4][2048][2048]
  u16* qb   = (u16*)(ws + 0 * MB);    // 48MB stacked x/k/v bf16 (dead after proj)
  u16* wqb  = (u16*)(ws + 48 * MB);   // 6MB  weights bf16 (dead after proj)
  u16* Vp   = (u16*)(ws + 54 * MB);   // 16MB (dead after transpose)
  u16* Vt   = (u16*)(ws + 70 * MB);   // 16MB
  u16* Kp   = (u16*)(ws + 86 * MB);   // 16MB
  u16* Qp   = (u16*)(ws + 102 * MB);  // 16MB  -> peak 118MB
  (void)in_sizes; (void)n_in; (void)out_size; (void)ws_size;

  // 1. casts (2 launches)
  cast3_f32_bf16<<<dim3(4096, 1, 3), 256, 0, stream>>>(q, k, v, qb, 8ull * MB);
  cast3_f32_bf16<<<dim3(512, 1, 3), 256, 0, stream>>>(Wq, Wk, Wv, wqb, 1ull * MB);

  // 2. stacked projections, 8-wave (1536 blocks, XCD-chunked)
  gemm_bt8<u16, 3><<<1536, 512, 0, stream>>>(
      qb, wqb, Qp, 1024, 1024, 1024, 1024,
      0, 1ull * MB, 0, 1.0f, Kp, Vp);

  // 3. V transpose -> Vt[4][1024][2048]
  transpose_bf16k<<<dim3(16, 32, 4), 256, 0, stream>>>(Vp, Vt);

  // 4. QK^T (scaled, tri-packed, XCD-swizzled, 8-wave) -> bf16 scores
  gemm_bt8<u16, 1><<<544, 512, 0, stream>>>(
      Qp, Kp, sc, 1024, 1024, 1024, 2048,
      (size_t)2048 * 1024, (size_t)2048 * 1024, (size_t)2048 * 2048, 0.03125f,
      nullptr, nullptr);

  // 5. causal softmax, bf16 in/out in place
  softmax_causal<<<8192, 256, 0, stream>>>(sc);

  // 6. PV: P[2048][2048] . Vt[1024][2048]^T -> out f32, longest-first, 8-wave
  gemm_bt8<float, 2><<<512, 512, 0, stream>>>(
      sc, Vt, out, 2048, 2048, 2048, 1024,
      (size_t)2048 * 2048, (size_t)1024 * 2048, (size_t)2048 * 1024, 1.0f,
      nullptr, nullptr);
}

// Round 11
// 179.001 us; speedup vs baseline: 1.0053x; 1.0053x over previous
//
#include <hip/hip_runtime.h>
#include <math.h>

using u16 = unsigned short;
typedef __attribute__((ext_vector_type(8))) __bf16 bf16x8;
typedef __attribute__((ext_vector_type(4))) float f32x4;
typedef __attribute__((ext_vector_type(4))) float f4v;
typedef __attribute__((ext_vector_type(8))) u16 u16x8;

__device__ __forceinline__ u16 f2bf(float f) {
  unsigned u = __float_as_uint(f);
  u += 0x7fffu + ((u >> 16) & 1u);   // round-to-nearest-even
  return (u16)(u >> 16);
}
__device__ __forceinline__ float bf2f(u16 b) {
  unsigned u = ((unsigned)b) << 16;
  return __uint_as_float(u);
}

__device__ __forceinline__ void gload16(const void* g, void* l) {
  __builtin_amdgcn_global_load_lds(
      (const __attribute__((address_space(1))) unsigned int*)g,
      (__attribute__((address_space(3))) unsigned int*)l, 16, 0, 0);
}

__device__ __forceinline__ f32x4 MF(bf16x8 a, bf16x8 b, f32x4 c) {
  return __builtin_amdgcn_mfma_f32_16x16x32_bf16(a, b, c, 0, 0, 0);
}

// ---------------------------------------------------------------- cast f32->bf16 (3 tensors)
__global__ __launch_bounds__(256) void cast3_f32_bf16(
    const float* __restrict__ p0, const float* __restrict__ p1,
    const float* __restrict__ p2, u16* __restrict__ out, size_t ostride) {
  int z = blockIdx.z;
  const float* in = (z == 0) ? p0 : (z == 1) ? p1 : p2;
  size_t i = ((size_t)blockIdx.x * 256 + threadIdx.x) * 8;
  f4v a = *reinterpret_cast<const f4v*>(in + i);
  f4v b = *reinterpret_cast<const f4v*>(in + i + 4);
  u16x8 r;
  r[0] = f2bf(a[0]); r[1] = f2bf(a[1]); r[2] = f2bf(a[2]); r[3] = f2bf(a[3]);
  r[4] = f2bf(b[0]); r[5] = f2bf(b[1]); r[6] = f2bf(b[2]); r[7] = f2bf(b[3]);
  *reinterpret_cast<u16x8*>(out + z * ostride + i) = r;
}

// ---------------------------------------------------------------- transpose+cast f32 W -> bf16 W^T
// z=0: Wk -> WkT; z=1: Wq -> WqT. out[e][d] = in[d][e].
__global__ __launch_bounds__(256) void tcast_w(
    const float* __restrict__ wk, const float* __restrict__ wq,
    u16* __restrict__ wkT, u16* __restrict__ wqT) {
  __shared__ float t[64][65];
  int z = blockIdx.z;
  const float* I = z ? wq : wk;
  u16* O = z ? wqT : wkT;
  int c0 = blockIdx.x * 64, r0 = blockIdx.y * 64;
  int tx = threadIdx.x & 63, ty = threadIdx.x >> 6;
  #pragma unroll
  for (int i = 0; i < 64; i += 4)
    t[ty + i][tx] = I[(size_t)(r0 + ty + i) * 1024 + c0 + tx];
  __syncthreads();
  #pragma unroll
  for (int i = 0; i < 64; i += 4)
    O[(size_t)(c0 + ty + i) * 1024 + r0 + tx] = f2bf(t[tx][ty + i]);
}

// ---------------------------------------------------------------- bf16 transpose
// in: [4][2048][1024]  -> out: [4][1024][2048]
__global__ __launch_bounds__(256) void transpose_bf16k(const u16* __restrict__ in,
                                                       u16* __restrict__ out) {
  __shared__ u16 t[64][65];
  int c0 = blockIdx.x * 64, r0 = blockIdx.y * 64;
  size_t zb = (size_t)blockIdx.z * 2048 * 1024;
  const u16* I = in + zb;
  u16* O = out + zb;
  int tx = threadIdx.x & 63, ty = threadIdx.x >> 6;
  #pragma unroll
  for (int i = 0; i < 64; i += 4)
    t[ty + i][tx] = I[(size_t)(r0 + ty + i) * 1024 + c0 + tx];
  __syncthreads();
  #pragma unroll
  for (int i = 0; i < 64; i += 4)
    O[(size_t)(c0 + ty + i) * 2048 + r0 + tx] = t[tx][ty + i];
}

// ================================================================ 8-wave 128x128 GEMM
// 2-phase dbuf, 512 threads = 8 waves (2M x 4N; wave out 64x32, acc[4][2],
// 8 MFMA/iter). Staging: wave w owns A-chunk w + B-chunk w (1KB each).
// MODE 0: plain (grid (M/128)*8, bm=idx>>3, bn=idx&7) — used for Mt.
// MODE 1: causal QK^T, tri-packed, XCD-swizzled, bf16 out (alpha pre-scale).
// MODE 2: causal PV, K clipped to (bm+1)*128, longest-first, f32 out.
// MODE 3: stacked 2-way projection: A rows stacked [2*8192][1024] (Xq,Xv);
//         weight slab B + which*sB (Mt, Wv); output {C, C1}; grid 1024.
template<typename OutT, int MODE>
__global__ __launch_bounds__(512) void gemm_bt8(
    const u16* __restrict__ A, const u16* __restrict__ B, OutT* __restrict__ C,
    int K, int lda, int ldb, int ldc,
    size_t sA, size_t sB, size_t sC, float alpha,
    OutT* __restrict__ C1) {
  int bn, bm, bz = 0;
  int kEnd = K;
  const u16 *Ag, *Bg;
  OutT* Cg;
  if (MODE == 0) {
    bm = blockIdx.x >> 3;
    bn = blockIdx.x & 7;
    Ag = A + (size_t)bm * 128 * lda;
    Bg = B + (size_t)bn * 128 * ldb;
    Cg = C;
  } else if (MODE == 1) {                // grid 544 = 4 * 136 lower-tri tiles
    int h = blockIdx.x;
    int l = (h & 7) * 68 + (h >> 3);
    bz = l / 136;
    int t = l % 136;
    bm = (int)((sqrtf(8.f * (float)t + 1.f) - 1.f) * 0.5f);
    while ((bm + 1) * (bm + 2) / 2 <= t) ++bm;
    while (bm * (bm + 1) / 2 > t) --bm;
    bn = t - bm * (bm + 1) / 2;
    Ag = A + sA * bz + (size_t)bm * 128 * lda;
    Bg = B + sB * bz + (size_t)bn * 128 * ldb;
    Cg = C + sC * bz;
  } else if (MODE == 2) {                // grid 512
    int l = blockIdx.x;
    bm = 15 - (l >> 5);                  // longest kEnd first
    int rest = l & 31;
    bz = rest >> 3;
    bn = rest & 7;
    kEnd = (K < (bm + 1) * 128) ? K : (bm + 1) * 128;
    Ag = A + sA * bz + (size_t)bm * 128 * lda;
    Bg = B + sB * bz + (size_t)bn * 128 * ldb;
    Cg = C + sC * bz;
  } else {                               // MODE 3, grid 1024, XCD-chunked
    int h = blockIdx.x;
    int l = (h & 7) * 128 + (h >> 3);
    bn = l & 7;
    int bm128 = l >> 3;
    int which = bm128 >> 6;
    bm = bm128 & 63;
    Ag = A + (size_t)bm128 * 128 * lda;
    Bg = B + (size_t)which * sB + (size_t)bn * 128 * ldb;
    Cg = (which == 0) ? C : C1;
  }

  __shared__ __align__(16) u16 As[2][128 * 32];
  __shared__ __align__(16) u16 Bs[2][128 * 32];

  const int tid = threadIdx.x;
  const int lane = tid & 63, wv = tid >> 6;   // 8 waves
  const int wr = wv >> 2, wc = wv & 3;        // 2M x 4N
  const int fr = lane & 15, kq = (lane >> 4) * 8;

  // staging: wave wv owns A-chunk wv + B-chunk wv (1KB each)
  const int e0 = wv * 512 + lane * 8;
  const int r0 = e0 >> 5, c0 = e0 & 31;
  const u16* a0 = Ag + (size_t)r0 * lda + c0;
  const u16* b0 = Bg + (size_t)r0 * ldb + c0;

  f32x4 acc[4][2] = {};
  const int nt = kEnd / 32;

  gload16(a0, &As[0][wv * 512]);
  gload16(b0, &Bs[0][wv * 512]);
  __syncthreads();

  for (int t = 0; t < nt; ++t) {
    const int cur = t & 1;
    if (t + 1 < nt) {
      const int k0 = (t + 1) * 32;
      gload16(a0 + k0, &As[cur ^ 1][wv * 512]);
      gload16(b0 + k0, &Bs[cur ^ 1][wv * 512]);
    }
    bf16x8 af[4], bfv[2];
    #pragma unroll
    for (int m = 0; m < 4; ++m)
      af[m] = *reinterpret_cast<const bf16x8*>(&As[cur][(wr * 64 + m * 16 + fr) * 32 + kq]);
    #pragma unroll
    for (int n = 0; n < 2; ++n)
      bfv[n] = *reinterpret_cast<const bf16x8*>(&Bs[cur][(wc * 32 + n * 16 + fr) * 32 + kq]);
    #pragma unroll
    for (int m = 0; m < 4; ++m)
      #pragma unroll
      for (int n = 0; n < 2; ++n)
        acc[m][n] = MF(af[m], bfv[n], acc[m][n]);
    __syncthreads();
  }

  const int row0 = bm * 128 + wr * 64 + (lane >> 4) * 4;
  const int col0 = bn * 128 + wc * 32 + fr;
  #pragma unroll
  for (int m = 0; m < 4; ++m)
    #pragma unroll
    for (int n = 0; n < 2; ++n) {
      #pragma unroll
      for (int j = 0; j < 4; ++j) {
        float val = acc[m][n][j] * alpha;
        size_t idx = (size_t)(row0 + m * 16 + j) * ldc + (col0 + n * 16);
        if constexpr (sizeof(OutT) == 2) Cg[idx] = f2bf(val);
        else Cg[idx] = val;
      }
    }
}

// ---------------------------------------------------------------- causal softmax (bf16 in/out, in-place)
__global__ __launch_bounds__(256) void softmax_causal(u16* __restrict__ sc) {
  int r = blockIdx.x;          // 0..8191
  int s = r & 2047;
  u16* row = sc + (size_t)r * 2048;
  int tid = threadIdx.x;
  int t0 = tid * 8;
  u16x8 raw = {0, 0, 0, 0, 0, 0, 0, 0};
  if (t0 <= s) raw = *reinterpret_cast<const u16x8*>(row + t0);
  float v[8];
  float mx = -1e30f;
  #pragma unroll
  for (int j = 0; j < 8; ++j) {
    v[j] = ((t0 + j) <= s) ? bf2f(raw[j]) : -1e30f;
    mx = fmaxf(mx, v[j]);
  }
  #pragma unroll
  for (int o = 32; o; o >>= 1) mx = fmaxf(mx, __shfl_xor(mx, o, 64));
  __shared__ float red[8];
  if ((tid & 63) == 0) red[tid >> 6] = mx;
  __syncthreads();
  mx = fmaxf(fmaxf(red[0], red[1]), fmaxf(red[2], red[3]));
  float p[8];
  float sum = 0.f;
  #pragma unroll
  for (int j = 0; j < 8; ++j) {
    p[j] = ((t0 + j) <= s) ? __expf(v[j] - mx) : 0.f;
    sum += p[j];
  }
  #pragma unroll
  for (int o = 32; o; o >>= 1) sum += __shfl_xor(sum, o, 64);
  if ((tid & 63) == 0) red[4 + (tid >> 6)] = sum;
  __syncthreads();
  sum = red[4] + red[5] + red[6] + red[7];
  float inv = 1.0f / sum;
  u16x8 o8;
  #pragma unroll
  for (int j = 0; j < 8; ++j) o8[j] = f2bf(p[j] * inv);
  if (t0 <= (s | 127))   // PV reads cols < (bm+1)*128 only
    *reinterpret_cast<u16x8*>(row + t0) = o8;
}

// ---------------------------------------------------------------- launcher
extern "C" void kernel_launch(void* const* d_in, const int* in_sizes, int n_in,
                              void* d_out, int out_size, void* d_ws, size_t ws_size,
                              hipStream_t stream) {
  const float* q  = (const float*)d_in[0];
  const float* k  = (const float*)d_in[1];
  const float* v  = (const float*)d_in[2];
  // d_in[3] = attn_mask (causal tril) — handled analytically
  const float* Wq = (const float*)d_in[4];
  const float* Wk = (const float*)d_in[5];
  const float* Wv = (const float*)d_in[6];
  float* out = (float*)d_out;
  char* ws = (char*)d_ws;

  const size_t MB = 1024ull * 1024ull;
  // W-merge: S = Xq.(Wq^T.Wk).Xk^T, so K-projection is replaced by Xk cast.
  // Liveness: qb slabs 0,1 (Xq,Xv) dead after proj -> sc (32MB) overlays them.
  // Xk (slab2) lives through QK. wkT/wqT dead after Mt; wsl dead after proj.
  u16* sc   = (u16*)ws;               // 0..32MB  bf16 scores [4][2048][2048]
  u16* qb   = (u16*)ws;               // slabs: 0=Xq, 1=Xv (16MB each, dead after proj)
  u16* xk   = (u16*)(ws + 32 * MB);   // slab2 = Xk bf16 (16MB, lives through QK)
  u16* wsl  = (u16*)(ws + 48 * MB);   // 4MB: slab0 = Mt, slab1 = Wv_bf
  u16* wkT  = (u16*)(ws + 52 * MB);   // 2MB (dead after Mt)
  u16* wqT  = (u16*)(ws + 54 * MB);   // 2MB (dead after Mt)
  u16* Vp   = (u16*)(ws + 56 * MB);   // 16MB (dead after transpose)
  u16* Vt   = (u16*)(ws + 72 * MB);   // 16MB
  u16* Yq   = (u16*)(ws + 88 * MB);   // 16MB  -> peak 104MB
  (void)in_sizes; (void)n_in; (void)out_size; (void)ws_size;

  // 1. big cast: z0=Xq->slab0, z1=Xv->slab1, z2=Xk->slab2
  cast3_f32_bf16<<<dim3(4096, 1, 3), 256, 0, stream>>>(q, v, k, qb, 8ull * MB);

  // 2. weight prep: WkT/WqT transpose-cast; Wv cast -> wsl slab1
  tcast_w<<<dim3(16, 16, 2), 256, 0, stream>>>(Wk, Wq, wkT, wqT);
  cast3_f32_bf16<<<dim3(512, 1, 1), 256, 0, stream>>>(Wv, nullptr, nullptr,
                                                      wsl + 1048576, 0);

  // 3. Mt = WkT . WqT^T = Wk^T.Wq  (Yq = Xq.Mt^T = Xq.Wq^T.Wk)
  gemm_bt8<u16, 0><<<64, 512, 0, stream>>>(
      wkT, wqT, wsl, 1024, 1024, 1024, 1024, 0, 0, 0, 1.0f, nullptr);

  // 4. 2-slab projection: Yq = Xq.Mt^T, Vp = Xv.Wv^T (1024 blocks, XCD-chunked)
  gemm_bt8<u16, 3><<<1024, 512, 0, stream>>>(
      qb, wsl, Yq, 1024, 1024, 1024, 1024,
      0, 1ull * MB, 0, 1.0f, Vp);

  // 5. V transpose -> Vt[4][1024][2048]
  transpose_bf16k<<<dim3(16, 32, 4), 256, 0, stream>>>(Vp, Vt);

  // 6. S = Yq . Xk^T (scaled, tri-packed, XCD-swizzled, 8-wave) -> bf16 scores
  gemm_bt8<u16, 1><<<544, 512, 0, stream>>>(
      Yq, xk, sc, 1024, 1024, 1024, 2048,
      (size_t)2048 * 1024, (size_t)2048 * 1024, (size_t)2048 * 2048, 0.03125f,
      nullptr);

  // 7. causal softmax, bf16 in/out in place
  softmax_causal<<<8192, 256, 0, stream>>>(sc);

  // 8. PV: P[2048][2048] . Vt[1024][2048]^T -> out f32, longest-first, 8-wave
  gemm_bt8<float, 2><<<512, 512, 0, stream>>>(
      sc, Vt, out, 2048, 2048, 2048, 1024,
      (size_t)2048 * 2048, (size_t)1024 * 2048, (size_t)2048 * 1024, 1.0f,
      nullptr);
}

// Round 12
// 170.803 us; speedup vs baseline: 1.0535x; 1.0480x over previous
//
#include <hip/hip_runtime.h>
#include <math.h>

using u16 = unsigned short;
typedef __attribute__((ext_vector_type(8))) __bf16 bf16x8;
typedef __attribute__((ext_vector_type(4))) float f32x4;
typedef __attribute__((ext_vector_type(4))) float f4v;
typedef __attribute__((ext_vector_type(8))) u16 u16x8;

__device__ __forceinline__ u16 f2bf(float f) {
  unsigned u = __float_as_uint(f);
  u += 0x7fffu + ((u >> 16) & 1u);   // round-to-nearest-even
  return (u16)(u >> 16);
}
__device__ __forceinline__ float bf2f(u16 b) {
  unsigned u = ((unsigned)b) << 16;
  return __uint_as_float(u);
}

__device__ __forceinline__ void gload16(const void* g, void* l) {
  __builtin_amdgcn_global_load_lds(
      (const __attribute__((address_space(1))) unsigned int*)g,
      (__attribute__((address_space(3))) unsigned int*)l, 16, 0, 0);
}

__device__ __forceinline__ f32x4 MF(bf16x8 a, bf16x8 b, f32x4 c) {
  return __builtin_amdgcn_mfma_f32_16x16x32_bf16(a, b, c, 0, 0, 0);
}

// ---------------------------------------------------------------- cast f32->bf16 (3 tensors)
__global__ __launch_bounds__(256) void cast3_f32_bf16(
    const float* __restrict__ p0, const float* __restrict__ p1,
    const float* __restrict__ p2, u16* __restrict__ out, size_t ostride) {
  int z = blockIdx.z;
  const float* in = (z == 0) ? p0 : (z == 1) ? p1 : p2;
  size_t i = ((size_t)blockIdx.x * 256 + threadIdx.x) * 8;
  f4v a = *reinterpret_cast<const f4v*>(in + i);
  f4v b = *reinterpret_cast<const f4v*>(in + i + 4);
  u16x8 r;
  r[0] = f2bf(a[0]); r[1] = f2bf(a[1]); r[2] = f2bf(a[2]); r[3] = f2bf(a[3]);
  r[4] = f2bf(b[0]); r[5] = f2bf(b[1]); r[6] = f2bf(b[2]); r[7] = f2bf(b[3]);
  *reinterpret_cast<u16x8*>(out + z * ostride + i) = r;
}

// ---------------------------------------------------------------- all weight prep, one dispatch
// z=0: Wk -> WkT (transpose-cast); z=1: Wq -> WqT; z=2: Wv -> wv_bf (plain cast).
__global__ __launch_bounds__(256) void wprep(
    const float* __restrict__ Wk, const float* __restrict__ Wq,
    const float* __restrict__ Wv, u16* __restrict__ wkT,
    u16* __restrict__ wqT, u16* __restrict__ wv_bf) {
  int z = blockIdx.z;
  if (z < 2) {
    __shared__ float t[64][65];
    const float* I = z ? Wq : Wk;
    u16* O = z ? wqT : wkT;
    int c0 = blockIdx.x * 64, r0 = blockIdx.y * 64;
    int tx = threadIdx.x & 63, ty = threadIdx.x >> 6;
    #pragma unroll
    for (int i = 0; i < 64; i += 4)
      t[ty + i][tx] = I[(size_t)(r0 + ty + i) * 1024 + c0 + tx];
    __syncthreads();
    #pragma unroll
    for (int i = 0; i < 64; i += 4)
      O[(size_t)(c0 + ty + i) * 1024 + r0 + tx] = f2bf(t[tx][ty + i]);
  } else {
    int b = blockIdx.y * 16 + blockIdx.x;           // 0..255
    size_t i = (size_t)b * 4096 + threadIdx.x * 16;
    #pragma unroll
    for (int h = 0; h < 2; ++h) {
      f4v a = *reinterpret_cast<const f4v*>(Wv + i + h * 8);
      f4v c = *reinterpret_cast<const f4v*>(Wv + i + h * 8 + 4);
      u16x8 r;
      r[0] = f2bf(a[0]); r[1] = f2bf(a[1]); r[2] = f2bf(a[2]); r[3] = f2bf(a[3]);
      r[4] = f2bf(c[0]); r[5] = f2bf(c[1]); r[6] = f2bf(c[2]); r[7] = f2bf(c[3]);
      *reinterpret_cast<u16x8*>(wv_bf + i + h * 8) = r;
    }
  }
}

// ================================================================ 8-wave 128x128 GEMM
// 2-phase dbuf, 512 threads = 8 waves (2M x 4N; wave out 64x32, acc[4][2],
// 8 MFMA/iter). Staging: wave w owns A-chunk w + B-chunk w (1KB each).
// MODE 0: plain (grid (M/128)*8) — used for Mt.
// MODE 1: causal QK^T, tri-packed, XCD-swizzled, bf16 out (alpha pre-scale).
// MODE 2: causal PV, K clipped to (bm+1)*128, longest-first, f32 out.
// MODE 3: stacked 2-way projection (Xq->Yq via Mt, Xv->Vt via Wv); the V slab
//         retransposes its output tile through LDS and writes Vt[e][t] directly.
template<typename OutT, int MODE>
__global__ __launch_bounds__(512) void gemm_bt8(
    const u16* __restrict__ A, const u16* __restrict__ B, OutT* __restrict__ C,
    int K, int lda, int ldb, int ldc,
    size_t sA, size_t sB, size_t sC, float alpha,
    OutT* __restrict__ C1) {
  int bn, bm, bz = 0;
  int kEnd = K;
  bool whichV = false;
  const u16 *Ag, *Bg;
  OutT* Cg;
  if (MODE == 0) {
    bm = blockIdx.x >> 3;
    bn = blockIdx.x & 7;
    Ag = A + (size_t)bm * 128 * lda;
    Bg = B + (size_t)bn * 128 * ldb;
    Cg = C;
  } else if (MODE == 1) {                // grid 544 = 4 * 136 lower-tri tiles
    int h = blockIdx.x;
    int l = (h & 7) * 68 + (h >> 3);
    bz = l / 136;
    int t = l % 136;
    bm = (int)((sqrtf(8.f * (float)t + 1.f) - 1.f) * 0.5f);
    while ((bm + 1) * (bm + 2) / 2 <= t) ++bm;
    while (bm * (bm + 1) / 2 > t) --bm;
    bn = t - bm * (bm + 1) / 2;
    Ag = A + sA * bz + (size_t)bm * 128 * lda;
    Bg = B + sB * bz + (size_t)bn * 128 * ldb;
    Cg = C + sC * bz;
  } else if (MODE == 2) {                // grid 512
    int l = blockIdx.x;
    bm = 15 - (l >> 5);                  // longest kEnd first
    int rest = l & 31;
    bz = rest >> 3;
    bn = rest & 7;
    kEnd = (K < (bm + 1) * 128) ? K : (bm + 1) * 128;
    Ag = A + sA * bz + (size_t)bm * 128 * lda;
    Bg = B + sB * bz + (size_t)bn * 128 * ldb;
    Cg = C + sC * bz;
  } else {                               // MODE 3, grid 1024, XCD-chunked
    int h = blockIdx.x;
    int l = (h & 7) * 128 + (h >> 3);
    bn = l & 7;
    int bm128 = l >> 3;
    whichV = (bm128 >> 6) != 0;
    bm = bm128 & 63;
    Ag = A + (size_t)bm128 * 128 * lda;
    Bg = B + (whichV ? sB : 0) + (size_t)bn * 128 * ldb;
    Cg = C;                              // used only for the Yq slab
  }

  // LDS: staging (2x8KB A + 2x8KB B = 32KB) reused post-loop as a
  // [128][129] u16 transpose tile (33,024B) by the V slab.
  __shared__ __align__(16) char smem[33024];
  u16* AsB = (u16*)smem;            // [2][4096]
  u16* BsB = AsB + 8192;            // [2][4096]

  const int tid = threadIdx.x;
  const int lane = tid & 63, wv = tid >> 6;   // 8 waves
  const int wr = wv >> 2, wc = wv & 3;        // 2M x 4N
  const int fr = lane & 15, kq = (lane >> 4) * 8;

  // staging: wave wv owns A-chunk wv + B-chunk wv (1KB each)
  const int e0 = wv * 512 + lane * 8;
  const int r0 = e0 >> 5, c0 = e0 & 31;
  const u16* a0 = Ag + (size_t)r0 * lda + c0;
  const u16* b0 = Bg + (size_t)r0 * ldb + c0;

  f32x4 acc[4][2] = {};
  const int nt = kEnd / 32;

  gload16(a0, &AsB[wv * 512]);
  gload16(b0, &BsB[wv * 512]);
  __syncthreads();

  for (int t = 0; t < nt; ++t) {
    const int cur = t & 1;
    if (t + 1 < nt) {
      const int k0 = (t + 1) * 32;
      gload16(a0 + k0, &AsB[(cur ^ 1) * 4096 + wv * 512]);
      gload16(b0 + k0, &BsB[(cur ^ 1) * 4096 + wv * 512]);
    }
    const u16* Ac = AsB + cur * 4096;
    const u16* Bc = BsB + cur * 4096;
    bf16x8 af[4], bfv[2];
    #pragma unroll
    for (int m = 0; m < 4; ++m)
      af[m] = *reinterpret_cast<const bf16x8*>(&Ac[(wr * 64 + m * 16 + fr) * 32 + kq]);
    #pragma unroll
    for (int n = 0; n < 2; ++n)
      bfv[n] = *reinterpret_cast<const bf16x8*>(&Bc[(wc * 32 + n * 16 + fr) * 32 + kq]);
    #pragma unroll
    for (int m = 0; m < 4; ++m)
      #pragma unroll
      for (int n = 0; n < 2; ++n)
        acc[m][n] = MF(af[m], bfv[n], acc[m][n]);
    __syncthreads();
  }

  if constexpr (MODE == 3) {
    if (whichV) {
      // retranspose 128x128 tile through LDS, write Vt[e][t] coalesced.
      u16* tt = (u16*)smem;
      #pragma unroll
      for (int m = 0; m < 4; ++m)
        #pragma unroll
        for (int n = 0; n < 2; ++n)
          #pragma unroll
          for (int j = 0; j < 4; ++j)
            tt[(wr * 64 + (lane >> 4) * 4 + m * 16 + j) * 129 +
               (wc * 32 + fr + n * 16)] = f2bf(acc[m][n][j]);
      __syncthreads();
      const int orow = tid >> 2, oc = (tid & 3) * 32;
      size_t base = (size_t)(bm >> 4) * (1024 * 2048) +
                    (size_t)(bn * 128 + orow) * 2048 +
                    (size_t)(bm & 15) * 128 + oc;
      #pragma unroll
      for (int jj = 0; jj < 4; ++jj) {
        u16x8 o;
        #pragma unroll
        for (int j = 0; j < 8; ++j) o[j] = tt[(oc + jj * 8 + j) * 129 + orow];
        *reinterpret_cast<u16x8*>(&C1[base + jj * 8]) = o;
      }
      return;
    }
  }

  const int row0 = bm * 128 + wr * 64 + (lane >> 4) * 4;
  const int col0 = bn * 128 + wc * 32 + fr;
  #pragma unroll
  for (int m = 0; m < 4; ++m)
    #pragma unroll
    for (int n = 0; n < 2; ++n) {
      #pragma unroll
      for (int j = 0; j < 4; ++j) {
        float val = acc[m][n][j] * alpha;
        size_t idx = (size_t)(row0 + m * 16 + j) * ldc + (col0 + n * 16);
        if constexpr (sizeof(OutT) == 2) Cg[idx] = f2bf(val);
        else Cg[idx] = val;
      }
    }
}

// ---------------------------------------------------------------- causal softmax (bf16 in/out, in-place)
__global__ __launch_bounds__(256) void softmax_causal(u16* __restrict__ sc) {
  int r = blockIdx.x;          // 0..8191
  int s = r & 2047;
  u16* row = sc + (size_t)r * 2048;
  int tid = threadIdx.x;
  int t0 = tid * 8;
  u16x8 raw = {0, 0, 0, 0, 0, 0, 0, 0};
  if (t0 <= s) raw = *reinterpret_cast<const u16x8*>(row + t0);
  float v[8];
  float mx = -1e30f;
  #pragma unroll
  for (int j = 0; j < 8; ++j) {
    v[j] = ((t0 + j) <= s) ? bf2f(raw[j]) : -1e30f;
    mx = fmaxf(mx, v[j]);
  }
  #pragma unroll
  for (int o = 32; o; o >>= 1) mx = fmaxf(mx, __shfl_xor(mx, o, 64));
  __shared__ float red[8];
  if ((tid & 63) == 0) red[tid >> 6] = mx;
  __syncthreads();
  mx = fmaxf(fmaxf(red[0], red[1]), fmaxf(red[2], red[3]));
  float p[8];
  float sum = 0.f;
  #pragma unroll
  for (int j = 0; j < 8; ++j) {
    p[j] = ((t0 + j) <= s) ? __expf(v[j] - mx) : 0.f;
    sum += p[j];
  }
  #pragma unroll
  for (int o = 32; o; o >>= 1) sum += __shfl_xor(sum, o, 64);
  if ((tid & 63) == 0) red[4 + (tid >> 6)] = sum;
  __syncthreads();
  sum = red[4] + red[5] + red[6] + red[7];
  float inv = 1.0f / sum;
  u16x8 o8;
  #pragma unroll
  for (int j = 0; j < 8; ++j) o8[j] = f2bf(p[j] * inv);
  if (t0 <= (s | 127))   // PV reads cols < (bm+1)*128 only
    *reinterpret_cast<u16x8*>(row + t0) = o8;
}

// ---------------------------------------------------------------- launcher
extern "C" void kernel_launch(void* const* d_in, const int* in_sizes, int n_in,
                              void* d_out, int out_size, void* d_ws, size_t ws_size,
                              hipStream_t stream) {
  const float* q  = (const float*)d_in[0];
  const float* k  = (const float*)d_in[1];
  const float* v  = (const float*)d_in[2];
  // d_in[3] = attn_mask (causal tril) — handled analytically
  const float* Wq = (const float*)d_in[4];
  const float* Wk = (const float*)d_in[5];
  const float* Wv = (const float*)d_in[6];
  float* out = (float*)d_out;
  char* ws = (char*)d_ws;

  const size_t MB = 1024ull * 1024ull;
  // W-merge: S = Xq.(Wq^T.Wk).Xk^T — K-projection replaced by the Xk cast.
  // sc (32MB) overlays qb slabs 0,1 (Xq,Xv — dead after proj). xk lives
  // through QK. wkT/wqT dead after Mt; wsl dead after proj. No Vp at all
  // (proj writes Vt directly, transposed).
  u16* sc   = (u16*)ws;               // 0..32MB  bf16 scores [4][2048][2048]
  u16* qb   = (u16*)ws;               // slabs: 0=Xq, 1=Xv (16MB each)
  u16* xk   = (u16*)(ws + 32 * MB);   // Xk bf16 (16MB, lives through QK)
  u16* wsl  = (u16*)(ws + 48 * MB);   // 4MB: slab0 = Mt, slab1 = Wv_bf
  u16* wkT  = (u16*)(ws + 52 * MB);   // 2MB (dead after Mt)
  u16* wqT  = (u16*)(ws + 54 * MB);   // 2MB (dead after Mt)
  u16* Vt   = (u16*)(ws + 56 * MB);   // 16MB (written by proj, read by PV)
  u16* Yq   = (u16*)(ws + 72 * MB);   // 16MB  -> peak 88MB
  (void)in_sizes; (void)n_in; (void)out_size; (void)ws_size;

  // 1. weight prep (one dispatch): WkT, WqT transpose-casts + Wv cast
  wprep<<<dim3(16, 16, 3), 256, 0, stream>>>(Wk, Wq, Wv, wkT, wqT,
                                             wsl + 1048576);

  // 2. Mt = WkT . WqT^T = Wk^T.Wq  (Yq = Xq.Mt^T = Xq.Wq^T.Wk)
  gemm_bt8<u16, 0><<<64, 512, 0, stream>>>(
      wkT, wqT, wsl, 1024, 1024, 1024, 1024, 0, 0, 0, 1.0f, nullptr);

  // 3. big cast: z0=Xq, z1=Xv, z2=Xk
  cast3_f32_bf16<<<dim3(4096, 1, 3), 256, 0, stream>>>(q, v, k, qb, 8ull * MB);

  // 4. 2-slab projection (1024 blocks): Yq = Xq.Mt^T; Vt = (Xv.Wv^T)^T in-epilogue
  gemm_bt8<u16, 3><<<1024, 512, 0, stream>>>(
      qb, wsl, Yq, 1024, 1024, 1024, 1024,
      0, 1048576, 0, 1.0f, Vt);

  // 5. S = Yq . Xk^T (scaled, tri-packed, XCD-swizzled) -> bf16 scores
  gemm_bt8<u16, 1><<<544, 512, 0, stream>>>(
      Yq, xk, sc, 1024, 1024, 1024, 2048,
      (size_t)2048 * 1024, (size_t)2048 * 1024, (size_t)2048 * 2048, 0.03125f,
      nullptr);

  // 6. causal softmax, bf16 in/out in place
  softmax_causal<<<8192, 256, 0, stream>>>(sc);

  // 7. PV: P[2048][2048] . Vt[1024][2048]^T -> out f32, longest-first
  gemm_bt8<float, 2><<<512, 512, 0, stream>>>(
      sc, Vt, out, 2048, 2048, 2048, 1024,
      (size_t)2048 * 2048, (size_t)1024 * 2048, (size_t)2048 * 1024, 1.0f,
      nullptr);
}